// Round 1
// baseline (517.062 us; speedup 1.0000x reference)
//
#include <hip/hip_runtime.h>

// TranslationIPA: B=1, N=512, CS=384, CZ=128, H=8, C=256, PQ=8, PV=12
// feats layout: [o 2048 | x 96 | y 96 | z 96 | norm 96 | o_pair 256] = 2688

#define NSEQ 512

// workspace float offsets
#define OFF_Q      0                         // 512*2048
#define OFF_KV     1048576                   // 512*4096
#define OFF_QPRAW  (OFF_KV + 2097152)        // 512*192
#define OFF_KVPRAW (OFF_QPRAW + 98304)       // 512*480
#define OFF_QPTS   (OFF_KVPRAW + 245760)     // 512*64*3
#define OFF_KVPTS  (OFF_QPTS + 98304)        // 512*160*3
#define OFF_BBIAS  (OFF_KVPTS + 245760)      // 512*512*8
#define OFF_PAIRZ  (OFF_BBIAS + 2097152)     // 512*512*32
#define OFF_ATTN   (OFF_PAIRZ + 8388608)     // 8*512*512
#define OFF_FEATS  (OFF_ATTN + 2097152)      // 512*2688

// ---------------- generic 64x64 f32 GEMM tile (K multiple of 16, M mult of 64) --------
__device__ __forceinline__ void sgemm_tile64(
    const float* __restrict__ A, const float* __restrict__ W,
    const float* bias /*nullable*/, float* __restrict__ Cout,
    const int K, const int Ncol, const int row0, const int col0,
    const int k0b, const int k1, const bool atomic,
    float (*As)[64], float (*Bs)[64]) {
  const int t  = threadIdx.x;
  const int tx = t & 15, ty = t >> 4;
  const int am = t >> 2, akq = (t & 3) << 2;
  const int bk = t >> 4, bn = (t & 15) << 2;
  float acc[4][4];
#pragma unroll
  for (int i = 0; i < 4; i++)
#pragma unroll
    for (int j = 0; j < 4; j++) acc[i][j] = 0.f;

  for (int k0 = k0b; k0 < k1; k0 += 16) {
    float4 a4 = *(const float4*)(A + (size_t)(row0 + am) * K + k0 + akq);
    float4 b4;
    {
      const float* wrow = W + (size_t)(k0 + bk) * Ncol;
      int col = col0 + bn;
      if (col + 3 < Ncol) b4 = *(const float4*)(wrow + col);
      else {
        b4.x = (col + 0 < Ncol) ? wrow[col + 0] : 0.f;
        b4.y = (col + 1 < Ncol) ? wrow[col + 1] : 0.f;
        b4.z = (col + 2 < Ncol) ? wrow[col + 2] : 0.f;
        b4.w = (col + 3 < Ncol) ? wrow[col + 3] : 0.f;
      }
    }
    __syncthreads();
    As[akq + 0][am] = a4.x; As[akq + 1][am] = a4.y;
    As[akq + 2][am] = a4.z; As[akq + 3][am] = a4.w;
    *(float4*)&Bs[bk][bn] = b4;
    __syncthreads();
#pragma unroll
    for (int kk = 0; kk < 16; kk++) {
      float4 av = *(const float4*)&As[kk][ty << 2];
      float4 bv = *(const float4*)&Bs[kk][tx << 2];
      acc[0][0] += av.x * bv.x; acc[0][1] += av.x * bv.y; acc[0][2] += av.x * bv.z; acc[0][3] += av.x * bv.w;
      acc[1][0] += av.y * bv.x; acc[1][1] += av.y * bv.y; acc[1][2] += av.y * bv.z; acc[1][3] += av.y * bv.w;
      acc[2][0] += av.z * bv.x; acc[2][1] += av.z * bv.y; acc[2][2] += av.z * bv.z; acc[2][3] += av.z * bv.w;
      acc[3][0] += av.w * bv.x; acc[3][1] += av.w * bv.y; acc[3][2] += av.w * bv.z; acc[3][3] += av.w * bv.w;
    }
  }
#pragma unroll
  for (int i = 0; i < 4; i++) {
    int row = row0 + (ty << 2) + i;
#pragma unroll
    for (int j = 0; j < 4; j++) {
      int col = col0 + (tx << 2) + j;
      if (col < Ncol) {
        float v = acc[i][j] + (bias ? bias[col] : 0.f);
        if (atomic) atomicAdd(&Cout[(size_t)row * Ncol + col], v);
        else Cout[(size_t)row * Ncol + col] = v;
      }
    }
  }
}

// ---------------- fused projections: s @ {wq,wkv,wqp,wkvp} --------------------------
__global__ __launch_bounds__(256) void proj_kernel(
    const float* __restrict__ s,
    const float* __restrict__ wq,  const float* __restrict__ bq,  float* __restrict__ qb,
    const float* __restrict__ wkv, const float* __restrict__ bkv, float* __restrict__ kvb,
    const float* __restrict__ wqp, const float* __restrict__ bqp, float* __restrict__ qpr,
    const float* __restrict__ wkvp,const float* __restrict__ bkvp,float* __restrict__ kvpr) {
  __shared__ float As[16][64], Bs[16][64];
  int bx = blockIdx.x, row0 = blockIdx.y * 64;
  const float *W, *bias; float* out; int Ncol, col0;
  if (bx < 32)      { W = wq;   bias = bq;   out = qb;   Ncol = 2048; col0 = bx * 64; }
  else if (bx < 96) { W = wkv;  bias = bkv;  out = kvb;  Ncol = 4096; col0 = (bx - 32) * 64; }
  else if (bx < 99) { W = wqp;  bias = bqp;  out = qpr;  Ncol = 192;  col0 = (bx - 96) * 64; }
  else              { W = wkvp; bias = bkvp; out = kvpr; Ncol = 480;  col0 = (bx - 99) * 64; }
  sgemm_tile64(s, W, bias, out, 384, Ncol, row0, col0, 0, 384, false, As, Bs);
}

// ---------------- rigid transform of point projections ------------------------------
__global__ __launch_bounds__(256) void rigid_pts(
    const float* __restrict__ qpraw, const float* __restrict__ kvpraw,
    const float* __restrict__ rot, const float* __restrict__ trans,
    float* __restrict__ qpts, float* __restrict__ kvpts) {
  int gid = blockIdx.x * 256 + threadIdx.x;  // 512*224 total, exact
  int n = gid / 224, r = gid % 224;
  const float* R  = rot + n * 9;
  const float* tr = trans + n * 3;
  float px, py, pz; float* dst;
  if (r < 64) {
    const float* src = qpraw + (size_t)n * 192;
    px = src[r]; py = src[64 + r]; pz = src[128 + r];
    dst = qpts + ((size_t)n * 64 + r) * 3;
  } else {
    int p = r - 64;
    const float* src = kvpraw + (size_t)n * 480;
    px = src[p]; py = src[160 + p]; pz = src[320 + p];
    dst = kvpts + ((size_t)n * 160 + p) * 3;
  }
  dst[0] = R[0] * px + R[1] * py + R[2] * pz + tr[0];
  dst[1] = R[3] * px + R[4] * py + R[5] * pz + tr[1];
  dst[2] = R[6] * px + R[7] * py + R[8] * pz + tr[2];
}

// ---------------- z-pass: bbias = z@wb+bb, pairz = z@wz+bz (one read of z) ----------
__global__ __launch_bounds__(256) void zpass_kernel(
    const float* __restrict__ z,
    const float* __restrict__ wb, const float* __restrict__ bb,
    const float* __restrict__ wz, const float* __restrict__ bz,
    float* __restrict__ bbias, float* __restrict__ pairz) {
  __shared__ float wS[128][44];  // cols 0..7 = wb, 8..39 = wz
  int t = threadIdx.x;
  for (int l = t; l < 128 * 40; l += 256) {
    int kk = l / 40, n = l % 40;
    wS[kk][n] = (n < 8) ? wb[kk * 8 + n] : wz[kk * 32 + (n - 8)];
  }
  __syncthreads();
  const int q = t & 3, rr = t >> 2;
  const size_t r0 = (size_t)blockIdx.x * 128 + rr * 2;
  const float* zr = z + r0 * 128;
  float acc[2][40];
#pragma unroll
  for (int i = 0; i < 2; i++)
#pragma unroll
    for (int j = 0; j < 40; j++) acc[i][j] = 0.f;

  for (int n4 = 0; n4 < 8; n4++) {
    const int kb = n4 * 16 + q * 4;
    float4 zA = *(const float4*)(zr + kb);
    float4 zB = *(const float4*)(zr + 128 + kb);
    float za[4] = {zA.x, zA.y, zA.z, zA.w};
    float zb4[4] = {zB.x, zB.y, zB.z, zB.w};
#pragma unroll
    for (int c = 0; c < 4; c++) {
      const float* wrow = &wS[kb + c][0];
#pragma unroll
      for (int g = 0; g < 10; g++) {
        float4 w4 = *(const float4*)(wrow + g * 4);
        acc[0][g*4+0] += za[c] * w4.x;  acc[0][g*4+1] += za[c] * w4.y;
        acc[0][g*4+2] += za[c] * w4.z;  acc[0][g*4+3] += za[c] * w4.w;
        acc[1][g*4+0] += zb4[c] * w4.x; acc[1][g*4+1] += zb4[c] * w4.y;
        acc[1][g*4+2] += zb4[c] * w4.z; acc[1][g*4+3] += zb4[c] * w4.w;
      }
    }
  }
  // reduce across q (lanes 4k..4k+3)
#pragma unroll
  for (int i = 0; i < 2; i++)
#pragma unroll
    for (int j = 0; j < 40; j++) {
      float v = acc[i][j];
      v += __shfl_xor(v, 1);
      v += __shfl_xor(v, 2);
      acc[i][j] = v;
    }
  if (q == 0) {
#pragma unroll
    for (int i = 0; i < 2; i++) {
      size_t r = r0 + i;
#pragma unroll
      for (int hh = 0; hh < 8; hh++)  bbias[r * 8 + hh]  = acc[i][hh] + bb[hh];
#pragma unroll
      for (int d = 0; d < 32; d++)    pairz[r * 32 + d]  = acc[i][8 + d] + bz[d];
    }
  }
}

// ---------------- attention logits (QK + point-att + bias + mask) -------------------
__global__ __launch_bounds__(256) void logits_kernel(
    const float* __restrict__ qb, const float* __restrict__ kvb,
    const float* __restrict__ qpts, const float* __restrict__ kvpts,
    const float* __restrict__ bbias, const float* __restrict__ mask,
    const float* __restrict__ hwp, float* __restrict__ attn) {
  const int jt = blockIdx.x, it = blockIdx.y, h = blockIdx.z;
  const int i0 = it * 16, j0 = jt * 64;
  __shared__ float qs[16][256];
  __shared__ float kt[64][33];
  __shared__ float qp_s[16][24];
  __shared__ float kp_s[64][25];
  const int t = threadIdx.x;

  for (int l = t; l < 16 * 64; l += 256) {
    int i = l >> 6, c4 = (l & 63) * 4;
    *(float4*)&qs[i][c4] = *(const float4*)(qb + (size_t)(i0 + i) * 2048 + h * 256 + c4);
  }
  for (int l = t; l < 16 * 24; l += 256) {
    int i = l / 24, w = l % 24;
    qp_s[i][w] = qpts[((size_t)(i0 + i) * 64 + h * 8) * 3 + w];
  }
  for (int l = t; l < 64 * 24; l += 256) {
    int jj = l / 24, w = l % 24;
    kp_s[jj][w] = kvpts[((size_t)(j0 + jj) * 160 + h * 20) * 3 + w];
  }

  const int jj = t & 63, ig = t >> 6;
  float acc[4] = {0.f, 0.f, 0.f, 0.f};

  for (int kc = 0; kc < 256; kc += 32) {
    __syncthreads();
    for (int l = t; l < 64 * 8; l += 256) {
      int r = l >> 3, cc4 = (l & 7) * 4;
      float4 k4 = *(const float4*)(kvb + (size_t)(j0 + r) * 4096 + h * 512 + kc + cc4);
      kt[r][cc4 + 0] = k4.x; kt[r][cc4 + 1] = k4.y;
      kt[r][cc4 + 2] = k4.z; kt[r][cc4 + 3] = k4.w;
    }
    __syncthreads();
#pragma unroll
    for (int cc = 0; cc < 32; cc += 4) {
      float k0v = kt[jj][cc], k1v = kt[jj][cc + 1], k2v = kt[jj][cc + 2], k3v = kt[jj][cc + 3];
#pragma unroll
      for (int ii = 0; ii < 4; ii++) {
        const float4 q4 = *(const float4*)&qs[ig * 4 + ii][kc + cc];
        acc[ii] += q4.x * k0v + q4.y * k1v + q4.z * k2v + q4.w * k3v;
      }
    }
  }

  const float hw = log1pf(expf(hwp[h])) * 0.09622504486493764f;  // sqrt(1/108)
  const float mj = mask[j0 + jj];
#pragma unroll
  for (int ii = 0; ii < 4; ii++) {
    const int i = ig * 4 + ii;
    float pt = 0.f;
#pragma unroll
    for (int p = 0; p < 8; p++) {
      float dx = qp_s[i][p * 3 + 0] - kp_s[jj][p * 3 + 0];
      float dy = qp_s[i][p * 3 + 1] - kp_s[jj][p * 3 + 1];
      float dz = qp_s[i][p * 3 + 2] - kp_s[jj][p * 3 + 2];
      pt += dx * dx + dy * dy + dz * dz;
    }
    float mi = mask[i0 + i];
    float b = bbias[((size_t)(i0 + i) * 512 + (j0 + jj)) * 8 + h];
    float logit = 0.03608439182435161f * acc[ii]      // 1/sqrt(768)
                + 0.5773502691896258f * b             // sqrt(1/3)
                - 0.5f * hw * pt
                + 100000.0f * (mi * mj - 1.0f);
    attn[((size_t)h * 512 + (i0 + i)) * 512 + (j0 + jj)] = logit;
  }
}

// ---------------- row softmax over j (512), in place --------------------------------
__global__ __launch_bounds__(256) void softmax_kernel(float* __restrict__ attn) {
  float* a = attn + (size_t)blockIdx.x * 512;
  const int t = threadIdx.x;
  float v0 = a[t], v1 = a[t + 256];
  __shared__ float redm[4], reds[4];
  float m = fmaxf(v0, v1);
#pragma unroll
  for (int o = 1; o < 64; o <<= 1) m = fmaxf(m, __shfl_xor(m, o));
  if ((t & 63) == 0) redm[t >> 6] = m;
  __syncthreads();
  m = fmaxf(fmaxf(redm[0], redm[1]), fmaxf(redm[2], redm[3]));
  float e0 = expf(v0 - m), e1 = expf(v1 - m);
  float s = e0 + e1;
#pragma unroll
  for (int o = 1; o < 64; o <<= 1) s += __shfl_xor(s, o);
  if ((t & 63) == 0) reds[t >> 6] = s;
  __syncthreads();
  float inv = 1.0f / (reds[0] + reds[1] + reds[2] + reds[3]);
  a[t] = e0 * inv;
  a[t + 256] = e1 * inv;
}

// ---------------- o = a@v, o_pt = a@v_pts (+inverse rigid, norm) ---------------------
__global__ __launch_bounds__(256) void attn_v_kernel(
    const float* __restrict__ attn, const float* __restrict__ kvb,
    const float* __restrict__ kvpts, const float* __restrict__ rot,
    const float* __restrict__ trans, float* __restrict__ feats) {
  const int it = blockIdx.x, h = blockIdx.y;
  const int i0 = it * 16;
  __shared__ float as[16][512];
  __shared__ float opt[16][36];
  const int t = threadIdx.x;
  for (int l = t; l < 16 * 128; l += 256) {
    int i = l >> 7, j4 = (l & 127) * 4;
    *(float4*)&as[i][j4] = *(const float4*)(attn + ((size_t)h * 512 + i0 + i) * 512 + j4);
  }
  __syncthreads();
  const int tx = t & 63, ty4 = (t >> 6) * 4;
  const bool do_p = tx < 36;
  const float* vbase = kvb + h * 512 + 256;
  const float* pbase = kvpts + (size_t)(h * 20 + 8) * 3;
  float acc[4][5];
#pragma unroll
  for (int i = 0; i < 4; i++)
#pragma unroll
    for (int j = 0; j < 5; j++) acc[i][j] = 0.f;

  for (int j = 0; j < 512; j += 4) {
    float4 av[4];
#pragma unroll
    for (int ii = 0; ii < 4; ii++) av[ii] = *(const float4*)&as[ty4 + ii][j];
#pragma unroll
    for (int u = 0; u < 4; u++) {
      const float* vr = vbase + (size_t)(j + u) * 4096;
      float v0 = vr[tx], v1 = vr[tx + 64], v2 = vr[tx + 128], v3 = vr[tx + 192];
      float vp = do_p ? pbase[(size_t)(j + u) * 480 + tx] : 0.f;
#pragma unroll
      for (int ii = 0; ii < 4; ii++) {
        float aa = ((const float*)&av[ii])[u];
        acc[ii][0] += aa * v0; acc[ii][1] += aa * v1;
        acc[ii][2] += aa * v2; acc[ii][3] += aa * v3;
        acc[ii][4] += aa * vp;
      }
    }
  }
#pragma unroll
  for (int ii = 0; ii < 4; ii++) {
    int i = ty4 + ii, irow = i0 + i;
    float* fr = feats + (size_t)irow * 2688;
#pragma unroll
    for (int g = 0; g < 4; g++) fr[h * 256 + tx + 64 * g] = acc[ii][g];
    if (do_p) opt[i][tx] = acc[ii][4];
  }
  __syncthreads();
  if (t < 192) {
    int i = t / 12, p = t % 12, irow = i0 + i;
    const float* R = rot + irow * 9;
    const float* tr = trans + irow * 3;
    float x = opt[i][p * 3 + 0] - tr[0];
    float y = opt[i][p * 3 + 1] - tr[1];
    float zz = opt[i][p * 3 + 2] - tr[2];
    float o0 = R[0] * x + R[3] * y + R[6] * zz;   // R^T v
    float o1 = R[1] * x + R[4] * y + R[7] * zz;
    float o2 = R[2] * x + R[5] * y + R[8] * zz;
    float nrm = sqrtf(o0 * o0 + o1 * o1 + o2 * o2 + 1e-8f);
    float* fr = feats + (size_t)irow * 2688 + 2048;
    fr[h * 12 + p]       = o0;
    fr[96 + h * 12 + p]  = o1;
    fr[192 + h * 12 + p] = o2;
    fr[288 + h * 12 + p] = nrm;
  }
}

// ---------------- o_pair = a @ pair_z (per query i) ----------------------------------
__global__ __launch_bounds__(256) void o_pair_kernel(
    const float* __restrict__ attn, const float* __restrict__ pairz,
    float* __restrict__ feats) {
  const int i = blockIdx.x;
  __shared__ float as[8][512];
  __shared__ float pzt[64][33];
  const int t = threadIdx.x;
  for (int l = t; l < 8 * 128; l += 256) {
    int hh = l >> 7, j4 = (l & 127) * 4;
    *(float4*)&as[hh][j4] = *(const float4*)(attn + ((size_t)hh * 512 + i) * 512 + j4);
  }
  const int h = t >> 5, d = t & 31;
  float acc = 0.f;
  for (int jt = 0; jt < 512; jt += 64) {
    __syncthreads();
    for (int l = t; l < 64 * 8; l += 256) {
      int j = l >> 3, d4 = (l & 7) * 4;
      float4 p4 = *(const float4*)(pairz + ((size_t)i * 512 + jt + j) * 32 + d4);
      pzt[j][d4 + 0] = p4.x; pzt[j][d4 + 1] = p4.y;
      pzt[j][d4 + 2] = p4.z; pzt[j][d4 + 3] = p4.w;
    }
    __syncthreads();
#pragma unroll
    for (int j = 0; j < 64; j += 4) {
      float4 a4 = *(const float4*)&as[h][jt + j];
      acc += a4.x * pzt[j][d] + a4.y * pzt[j + 1][d] + a4.z * pzt[j + 2][d] + a4.w * pzt[j + 3][d];
    }
  }
  feats[(size_t)i * 2688 + 2432 + h * 32 + d] = acc;
}

// ---------------- final GEMM: out = feats @ wo + bo (split-K=4, atomic) --------------
__global__ __launch_bounds__(256) void out_gemm_kernel(
    const float* __restrict__ feats, const float* __restrict__ wo,
    const float* __restrict__ bo, float* __restrict__ out) {
  __shared__ float As[16][64], Bs[16][64];
  int col0 = blockIdx.x * 64, row0 = blockIdx.y * 64;
  int k0 = blockIdx.z * 672;
  sgemm_tile64(feats, wo, blockIdx.z == 0 ? bo : nullptr, out,
               2688, 384, row0, col0, k0, k0 + 672, true, As, Bs);
}

extern "C" void kernel_launch(void* const* d_in, const int* in_sizes, int n_in,
                              void* d_out, int out_size, void* d_ws, size_t ws_size,
                              hipStream_t stream) {
  const float* s     = (const float*)d_in[0];
  const float* z     = (const float*)d_in[1];
  const float* rot   = (const float*)d_in[2];
  const float* trans = (const float*)d_in[3];
  const float* mask  = (const float*)d_in[4];
  const float* wq    = (const float*)d_in[5];
  const float* bq    = (const float*)d_in[6];
  const float* wkv   = (const float*)d_in[7];
  const float* bkv   = (const float*)d_in[8];
  const float* wqp   = (const float*)d_in[9];
  const float* bqp   = (const float*)d_in[10];
  const float* wkvp  = (const float*)d_in[11];
  const float* bkvp  = (const float*)d_in[12];
  const float* wb    = (const float*)d_in[13];
  const float* bb    = (const float*)d_in[14];
  const float* wz    = (const float*)d_in[15];
  const float* bz    = (const float*)d_in[16];
  const float* hwp   = (const float*)d_in[17];
  const float* wo    = (const float*)d_in[18];
  const float* bo    = (const float*)d_in[19];
  float* out = (float*)d_out;

  float* ws = (float*)d_ws;
  float* qb     = ws + OFF_Q;
  float* kvb    = ws + OFF_KV;
  float* qpraw  = ws + OFF_QPRAW;
  float* kvpraw = ws + OFF_KVPRAW;
  float* qpts   = ws + OFF_QPTS;
  float* kvpts  = ws + OFF_KVPTS;
  float* bbias  = ws + OFF_BBIAS;
  float* pairz  = ws + OFF_PAIRZ;
  float* attn   = ws + OFF_ATTN;
  float* feats  = ws + OFF_FEATS;

  proj_kernel<<<dim3(107, 8), 256, 0, stream>>>(s, wq, bq, qb, wkv, bkv, kvb,
                                                wqp, bqp, qpraw, wkvp, bkvp, kvpraw);
  rigid_pts<<<448, 256, 0, stream>>>(qpraw, kvpraw, rot, trans, qpts, kvpts);
  zpass_kernel<<<2048, 256, 0, stream>>>(z, wb, bb, wz, bz, bbias, pairz);
  logits_kernel<<<dim3(8, 32, 8), 256, 0, stream>>>(qb, kvb, qpts, kvpts, bbias, mask, hwp, attn);
  softmax_kernel<<<4096, 256, 0, stream>>>(attn);
  attn_v_kernel<<<dim3(32, 8), 256, 0, stream>>>(attn, kvb, kvpts, rot, trans, feats);
  o_pair_kernel<<<512, 256, 0, stream>>>(attn, pairz, feats);
  (void)hipMemsetAsync(out, 0, (size_t)out_size * sizeof(float), stream);
  out_gemm_kernel<<<dim3(6, 8, 4), 256, 0, stream>>>(feats, wo, bo, out);
}